// Round 1
// baseline (14605.386 us; speedup 1.0000x reference)
//
#include <hip/hip_runtime.h>

#define Bsz 32
#define Ssz 1024
#define Isz 128
#define Hsz 512
#define Lsz 3

// Tiled dot: each of 256 threads computes dot(in[b, :K], W[jg*8+jj, :K]) where
// b = tid&31, jj = tid>>5. Input slab (32 x 128) and weight slab (8 x 128)
// staged through LDS per 128-wide k-tile.
__device__ __forceinline__ float tile_dot(
    const float* __restrict__ inb, long instride,
    const float* __restrict__ Wjg, int K,
    int tid, float* __restrict__ hs, float* __restrict__ wsh)
{
  const int b  = tid & 31;
  const int jj = tid >> 5;
  float4 a = make_float4(0.f, 0.f, 0.f, 0.f);
  for (int k0 = 0; k0 < K; k0 += 128) {
    __syncthreads();  // previous tile fully consumed
    // stage 32 x 128 input slab (stride 132 to dodge worst bank conflicts)
#pragma unroll
    for (int i = 0; i < 4; ++i) {
      int e = tid + 256 * i;
      int row = e >> 5, c4 = e & 31;
      float4 v = *(const float4*)(inb + (long)row * instride + k0 + c4 * 4);
      *(float4*)&hs[row * 132 + c4 * 4] = v;
    }
    {  // stage 8 x 128 weight slab
      int row = tid >> 5, c4 = tid & 31;
      float4 v = *(const float4*)(Wjg + (long)row * K + k0 + c4 * 4);
      *(float4*)&wsh[row * 128 + c4 * 4] = v;
    }
    __syncthreads();
#pragma unroll
    for (int k = 0; k < 128; k += 4) {
      float4 hv = *(const float4*)&hs[b * 132 + k];
      float4 wv = *(const float4*)&wsh[jj * 128 + k];
      a.x += hv.x * wv.x;
      a.y += hv.y * wv.y;
      a.z += hv.z * wv.z;
      a.w += hv.w * wv.w;
    }
  }
  return (a.x + a.y) + (a.z + a.w);
}

// One pipelined wavefront slot: block blk handles layer l = blk/64,
// j-group jg = blk%64 (8 output columns), all 32 batches, at time te = t - l.
// h_new = tanh(Wih . in_te + bih + Whh . h_{te-1} + bhh)
__global__ __launch_bounds__(256) void rnn_step(
    const float* __restrict__ x, const float* __restrict__ h0,
    const float* __restrict__ w_ih0, const float* __restrict__ w_ihs,
    const float* __restrict__ w_hhs, const float* __restrict__ b_ihs,
    const float* __restrict__ b_hhs,
    float* __restrict__ out0, float* __restrict__ out1,
    float* __restrict__ out2, int t)
{
  __shared__ float hs[32 * 132];
  __shared__ float wsh[8 * 128];
  const int blk = blockIdx.x;
  const int l = blk >> 6;
  const int jg = blk & 63;
  const int te = t - l;
  if (te < 0 || te >= Ssz) return;  // uniform per block
  const int tid = threadIdx.x;
  const int b  = tid & 31;
  const int jj = tid >> 5;
  const int j = jg * 8 + jj;

  float* out_l = (l == 0) ? out0 : ((l == 1) ? out1 : out2);

  const float* in_base;
  long in_stride;
  const float* Wih;
  int Kin;
  if (l == 0) {
    in_base = x + (long)te * Isz;
    in_stride = (long)Ssz * Isz;
    Wih = w_ih0 + (long)jg * 8 * Isz;
    Kin = Isz;
  } else {
    const float* src = (l == 1) ? out0 : out1;
    in_base = src + (long)te * Hsz;
    in_stride = (long)Ssz * Hsz;
    Wih = w_ihs + (long)(l - 1) * Hsz * Hsz + (long)jg * 8 * Hsz;
    Kin = Hsz;
  }
  const float* hp_base;
  long hp_stride;
  if (te == 0) {
    hp_base = h0 + (long)l * Bsz * Hsz;
    hp_stride = Hsz;
  } else {
    hp_base = out_l + (long)(te - 1) * Hsz;
    hp_stride = (long)Ssz * Hsz;
  }
  const float* Whh = w_hhs + (long)l * Hsz * Hsz + (long)jg * 8 * Hsz;

  float acc = b_ihs[l * Hsz + j] + b_hhs[l * Hsz + j];
  acc += tile_dot(in_base, in_stride, Wih, Kin, tid, hs, wsh);
  acc += tile_dot(hp_base, hp_stride, Whh, Hsz, tid, hs, wsh);
  out_l[((long)b * Ssz + te) * Hsz + j] = tanhf(acc);
}

// hidden[l][b][j] = out_l[b][S-1][j]
__global__ __launch_bounds__(256) void copy_finals(
    const float* __restrict__ out0, const float* __restrict__ out1,
    const float* __restrict__ out2, float* __restrict__ hidden)
{
  int idx = blockIdx.x * 256 + threadIdx.x;
  if (idx >= Lsz * Bsz * Hsz) return;
  int l = idx / (Bsz * Hsz);
  int r = idx % (Bsz * Hsz);
  int b = r / Hsz, j = r % Hsz;
  const float* o = (l == 0) ? out0 : ((l == 1) ? out1 : out2);
  hidden[idx] = o[((long)b * Ssz + (Ssz - 1)) * Hsz + j];
}

extern "C" void kernel_launch(void* const* d_in, const int* in_sizes, int n_in,
                              void* d_out, int out_size, void* d_ws, size_t ws_size,
                              hipStream_t stream) {
  const float* x     = (const float*)d_in[0];
  const float* h0    = (const float*)d_in[1];
  const float* w_ih0 = (const float*)d_in[2];
  const float* w_ihs = (const float*)d_in[3];
  const float* w_hhs = (const float*)d_in[4];
  const float* b_ihs = (const float*)d_in[5];
  const float* b_hhs = (const float*)d_in[6];

  float* outp   = (float*)d_out;
  float* hidden = outp;                            // [L,B,H] = 49152
  float* out2   = outp + (long)Lsz * Bsz * Hsz;    // [B,S,H] final-layer outputs
  float* out0   = (float*)d_ws;                    // [B,S,H] layer-0 outputs
  float* out1   = out0 + (long)Bsz * Ssz * Hsz;    // [B,S,H] layer-1 outputs

  // Pipelined wavefront over time: launch t computes (l=0,t),(l=1,t-1),(l=2,t-2)
  for (int t = 0; t < Ssz + Lsz - 1; ++t) {
    rnn_step<<<Lsz * 64, 256, 0, stream>>>(x, h0, w_ih0, w_ihs, w_hhs,
                                           b_ihs, b_hhs, out0, out1, out2, t);
  }
  copy_finals<<<(Lsz * Bsz * Hsz + 255) / 256, 256, 0, stream>>>(out0, out1, out2, hidden);
}

// Round 2
// 7630.602 us; speedup vs baseline: 1.9141x; 1.9141x over previous
//
#include <hip/hip_runtime.h>

// Persistent 3-layer tanh-RNN, B=32, S=1024, I=128, H=512.
// f16 split-2 (hi + lo*2^-12) x 3 MFMA products == fp32-class precision.
// 96 blocks = 3 layers x 16 j-groups(32 j) x 2 b-groups(16 b); weights live in
// VGPRs as MFMA B-frags for the whole kernel; flag-based producer/consumer
// sync (agent scope) between layers/steps; timeout-bounded polls (no hangs).

typedef _Float16 half8 __attribute__((ext_vector_type(8)));
typedef float f32x4 __attribute__((ext_vector_type(4)));
typedef unsigned int uint32;
typedef unsigned short ushort16;

#define SCOPE_AGENT __HIP_MEMORY_SCOPE_AGENT
#define PLANE_ELEMS (32 * 1024 * 512)

__device__ __forceinline__ half8 h8(uint32 a, uint32 b, uint32 c, uint32 d) {
  union { uint32 u[4]; half8 h; } x;
  x.u[0] = a; x.u[1] = b; x.u[2] = c; x.u[3] = d;
  return x.h;
}

// pair dword: low16 = hi-f16 bits, high16 = lo-f16 bits
__device__ __forceinline__ void unpack_pair8(uint4 a, uint4 b, half8& hi, half8& lo) {
  hi = h8((a.x & 0xFFFFu) | (a.y << 16),
          (a.z & 0xFFFFu) | (a.w << 16),
          (b.x & 0xFFFFu) | (b.y << 16),
          (b.z & 0xFFFFu) | (b.w << 16));
  lo = h8((a.x >> 16) | (a.y & 0xFFFF0000u),
          (a.z >> 16) | (a.w & 0xFFFF0000u),
          (b.x >> 16) | (b.y & 0xFFFF0000u),
          (b.z >> 16) | (b.w & 0xFFFF0000u));
}

__device__ __forceinline__ void split8f(const float* v, half8& hi, half8& lo) {
  union { _Float16 e[8]; half8 h; } H, L;
#pragma unroll
  for (int i = 0; i < 8; ++i) {
    _Float16 h = (_Float16)v[i];
    H.e[i] = h;
    L.e[i] = (_Float16)((v[i] - (float)h) * 4096.0f);  // exact residual, scaled into f16 normal range
  }
  hi = H.h; lo = L.h;
}

__device__ __forceinline__ uint32 pack_pair(float xx) {
  _Float16 h = (_Float16)xx;
  _Float16 l = (_Float16)((xx - (float)h) * 4096.0f);
  union { _Float16 f; ushort16 u; } ch, cl;
  ch.f = h; cl.f = l;
  return (uint32)ch.u | ((uint32)cl.u << 16);
}

__device__ __forceinline__ void frag_from_f32(const float* p, half8& hi, half8& lo) {
  float v[8];
  *(float4*)(v)     = *(const float4*)(p);
  *(float4*)(v + 4) = *(const float4*)(p + 4);
  split8f(v, hi, lo);
}

__device__ __forceinline__ void frag_from_pairs(const uint32* p, half8& hi, half8& lo) {
  uint4 a = *(const uint4*)p;
  uint4 b = *(const uint4*)(p + 4);
  unpack_pair8(a, b, hi, lo);
}

// timeout-bounded flag wait (tid 0 only). ~75ms budget -> degrades, never hangs.
__device__ __forceinline__ bool waitflag(uint32* flags, int fi, uint32 target) {
  int spins = 0;
  while (__hip_atomic_load(&flags[fi], __ATOMIC_RELAXED, SCOPE_AGENT) < target) {
    __builtin_amdgcn_s_sleep(8);
    if (++spins > 200000) return false;
  }
  (void)__hip_atomic_load(&flags[fi], __ATOMIC_ACQUIRE, SCOPE_AGENT);  // inv caches
  return true;
}

template <int L>
__device__ void run_layer(const float* __restrict__ x, const float* __restrict__ h0,
                          const float* __restrict__ w_ih0, const float* __restrict__ w_ihs,
                          const float* __restrict__ w_hhs, const float* __restrict__ b_ihs,
                          const float* __restrict__ b_hhs, uint32* __restrict__ plane0,
                          uint32* __restrict__ plane1, float* __restrict__ outp, int jg, int bg) {
  constexpr int NKT = (L == 0) ? 20 : 32;   // K-tiles of 32 (l0: 4 x-tiles + 16 rec; else 16 in + 16 rec)
  constexpr int KTN = NKT / 4;              // tiles per wave
  constexpr int RECKT = (L == 0) ? 4 : 16;  // first recurrent tile

  uint32* flags = (uint32*)outp;            // 3*1024 counters in the (dead) hidden region
  float* hidden = outp;
  float* out2 = outp + 3 * 32 * 512;

  const int tid = threadIdx.x;
  const int w = tid >> 6;
  const int lane = tid & 63;
  const int ln16 = lane & 15;
  const int kgrp = lane >> 4;               // frag k-group: k8 = kgrp*8
  const int j0 = jg * 32;
  const int jc0 = j0 + ln16;                // jtile-0 column for this lane
  const int jc1 = j0 + 16 + ln16;           // jtile-1 column
  const int bloc = bg * 16 + ln16;          // A-frag row (batch)
  const int ktb = w * KTN;

  __shared__ f32x4 red[3 * 2 * 64];
  __shared__ int s_abort;
  if (tid == 0) s_abort = 0;

  // ---- preload weights (step-invariant) into VGPRs as hi/lo B-frags ----
  half8 Bhi[2][KTN], Blo[2][KTN];
#pragma unroll
  for (int jt = 0; jt < 2; ++jt) {
    const int j = j0 + jt * 16 + ln16;
#pragma unroll
    for (int ktl = 0; ktl < KTN; ++ktl) {
      const int kt = ktb + ktl;
      const float* wp;
      if (L == 0) {
        if (kt < 4) wp = w_ih0 + j * 128 + kt * 32 + kgrp * 8;
        else        wp = w_hhs + j * 512 + (kt - 4) * 32 + kgrp * 8;
      } else {
        if (kt < 16) wp = w_ihs + (L - 1) * 512 * 512 + j * 512 + kt * 32 + kgrp * 8;
        else         wp = w_hhs + L * 512 * 512 + j * 512 + (kt - 16) * 32 + kgrp * 8;
      }
      frag_from_f32(wp, Bhi[jt][ktl], Blo[jt][ktl]);
    }
  }

  const float bias0 = b_ihs[L * 512 + jc0] + b_hhs[L * 512 + jc0];
  const float bias1 = b_ihs[L * 512 + jc1] + b_hhs[L * 512 + jc1];
  uint32* myplane = (L == 0) ? plane0 : plane1;  // L==2 never uses it
  __syncthreads();

  for (int t = 0; t < 1024; ++t) {
    // ---- gate: own h_{t-1} (siblings) and upstream in_t ----
    if (tid == 0) {
      bool ok = true;
      if (t > 0) ok = waitflag(flags, L * 1024 + (t - 1), 32u);
      if (ok && L > 0) ok = waitflag(flags, (L - 1) * 1024 + t, 32u);
      if (!ok) s_abort = 1;
    }
    __syncthreads();
    if (s_abort) break;

    // ---- per-step source row pointers ----
    const float* recF = nullptr; const uint32* recP = nullptr;
    if (t == 0)      recF = h0 + (L * 32 + bloc) * 512;
    else if (L < 2)  recP = myplane + ((t - 1) * 32 + bloc) * 512;
    else             recF = out2 + (bloc * 1024 + (t - 1)) * 512;

    const float* inF = nullptr; const uint32* inP = nullptr;
    if (L == 0)      inF = x + (bloc * 1024 + t) * 128;
    else if (L == 1) inP = plane0 + (t * 32 + bloc) * 512;
    else             inP = plane1 + (t * 32 + bloc) * 512;

    f32x4 C0 = {0.f, 0.f, 0.f, 0.f}, C1 = C0, X0 = C0, X1 = C0;

#pragma unroll
    for (int ktl = 0; ktl < KTN; ++ktl) {
      const int kt = ktb + ktl;
      half8 Ahi, Alo;
      if (kt < RECKT) {  // input half
        const int k = kt * 32 + kgrp * 8;
        if (L == 0) frag_from_f32(inF + k, Ahi, Alo);
        else        frag_from_pairs(inP + k, Ahi, Alo);
      } else {           // recurrent half
        const int k = (kt - RECKT) * 32 + kgrp * 8;
        if (t == 0 || L == 2) frag_from_f32(recF + k, Ahi, Alo);
        else                  frag_from_pairs(recP + k, Ahi, Alo);
      }
      C0 = __builtin_amdgcn_mfma_f32_16x16x32_f16(Ahi, Bhi[0][ktl], C0, 0, 0, 0);
      C1 = __builtin_amdgcn_mfma_f32_16x16x32_f16(Ahi, Bhi[1][ktl], C1, 0, 0, 0);
      X0 = __builtin_amdgcn_mfma_f32_16x16x32_f16(Ahi, Blo[0][ktl], X0, 0, 0, 0);
      X1 = __builtin_amdgcn_mfma_f32_16x16x32_f16(Ahi, Blo[1][ktl], X1, 0, 0, 0);
      X0 = __builtin_amdgcn_mfma_f32_16x16x32_f16(Alo, Bhi[0][ktl], X0, 0, 0, 0);
      X1 = __builtin_amdgcn_mfma_f32_16x16x32_f16(Alo, Bhi[1][ktl], X1, 0, 0, 0);
    }

    f32x4 P0 = C0 + X0 * (1.0f / 4096.0f);
    f32x4 P1 = C1 + X1 * (1.0f / 4096.0f);

    if (w > 0) {
      red[((w - 1) * 2 + 0) * 64 + lane] = P0;
      red[((w - 1) * 2 + 1) * 64 + lane] = P1;
    }
    __syncthreads();

    if (w == 0) {
#pragma unroll
      for (int wv = 0; wv < 3; ++wv) {
        P0 += red[(wv * 2 + 0) * 64 + lane];
        P1 += red[(wv * 2 + 1) * 64 + lane];
      }
      const int brow = bg * 16 + kgrp * 4;  // C/D: col=lane&15, row=(lane>>4)*4+r
#pragma unroll
      for (int r = 0; r < 4; ++r) {
        const float y0 = tanhf(P0[r] + bias0);
        const float y1 = tanhf(P1[r] + bias1);
        const int b = brow + r;
        if (L < 2) {
          __hip_atomic_store(&myplane[(t * 32 + b) * 512 + jc0], pack_pair(y0), __ATOMIC_RELAXED, SCOPE_AGENT);
          __hip_atomic_store(&myplane[(t * 32 + b) * 512 + jc1], pack_pair(y1), __ATOMIC_RELAXED, SCOPE_AGENT);
        } else {
          __hip_atomic_store(&out2[(b * 1024 + t) * 512 + jc0], y0, __ATOMIC_RELAXED, SCOPE_AGENT);
          __hip_atomic_store(&out2[(b * 1024 + t) * 512 + jc1], y1, __ATOMIC_RELAXED, SCOPE_AGENT);
          if (t == 1023) {
            hidden[2 * 32 * 512 + b * 512 + jc0] = y0;
            hidden[2 * 32 * 512 + b * 512 + jc1] = y1;
          }
        }
      }
      if (lane == 0)
        __hip_atomic_fetch_add(&flags[L * 1024 + t], 1u, __ATOMIC_RELEASE, SCOPE_AGENT);
    }
  }
}

__global__ __launch_bounds__(256) void rnn_persist(
    const float* __restrict__ x, const float* __restrict__ h0,
    const float* __restrict__ w_ih0, const float* __restrict__ w_ihs,
    const float* __restrict__ w_hhs, const float* __restrict__ b_ihs,
    const float* __restrict__ b_hhs, uint32* __restrict__ plane0,
    uint32* __restrict__ plane1, float* __restrict__ outp) {
  const int bid = blockIdx.x;
  const int l = bid >> 5;
  const int idx = bid & 31;
  const int jg = idx >> 1;
  const int bg = idx & 1;
  if (l == 0)      run_layer<0>(x, h0, w_ih0, w_ihs, w_hhs, b_ihs, b_hhs, plane0, plane1, outp, jg, bg);
  else if (l == 1) run_layer<1>(x, h0, w_ih0, w_ihs, w_hhs, b_ihs, b_hhs, plane0, plane1, outp, jg, bg);
  else             run_layer<2>(x, h0, w_ih0, w_ihs, w_hhs, b_ihs, b_hhs, plane0, plane1, outp, jg, bg);
}

// hidden[l][b][j] for l in {0,1} from the last pair-plane slot (exact-ish: hi + lo*2^-12)
__global__ __launch_bounds__(256) void finals_kernel(const uint32* __restrict__ plane0,
                                                     const uint32* __restrict__ plane1,
                                                     float* __restrict__ outp) {
  int i = blockIdx.x * 256 + threadIdx.x;
  if (i >= 2 * 32 * 512) return;
  int l = i >> 14;
  int r = i & 16383;  // b*512 + j
  const uint32* pl = l ? plane1 : plane0;
  uint32 p = pl[1023 * 32 * 512 + r];
  union { ushort16 u; _Float16 f; } h, lo;
  h.u = (ushort16)(p & 0xFFFFu);
  lo.u = (ushort16)(p >> 16);
  outp[i] = (float)h.f + (float)lo.f * (1.0f / 4096.0f);
}

extern "C" void kernel_launch(void* const* d_in, const int* in_sizes, int n_in,
                              void* d_out, int out_size, void* d_ws, size_t ws_size,
                              hipStream_t stream) {
  const float* x     = (const float*)d_in[0];
  const float* h0    = (const float*)d_in[1];
  const float* w_ih0 = (const float*)d_in[2];
  const float* w_ihs = (const float*)d_in[3];
  const float* w_hhs = (const float*)d_in[4];
  const float* b_ihs = (const float*)d_in[5];
  const float* b_hhs = (const float*)d_in[6];

  uint32* plane0 = (uint32*)d_ws;            // layer-0 outputs, (hi,lo) f16 pairs, 64 MB
  uint32* plane1 = plane0 + PLANE_ELEMS;     // layer-1 outputs, 64 MB (total == round-1's proven 134.2 MB)

  // zero the flag counters (they live in the hidden region of d_out, rewritten at the end)
  hipMemsetAsync(d_out, 0, 3 * 1024 * sizeof(uint32), stream);
  rnn_persist<<<96, 256, 0, stream>>>(x, h0, w_ih0, w_ihs, w_hhs, b_ihs, b_hhs,
                                      plane0, plane1, (float*)d_out);
  finals_kernel<<<128, 256, 0, stream>>>(plane0, plane1, (float*)d_out);
}